// Round 3
// baseline (4064.552 us; speedup 1.0000x reference)
//
#include <hip/hip_runtime.h>
#include <hip/hip_bf16.h>

// Round 3 resubmit (rounds 1-2 hit GPUAcquisitionTimeout; no data yet).
// fp32 correctness baseline for chunkwise delta-rule linear attention.
//
// Kernel A (one block per chunk, 2048 blocks):
//   normalize k,q rows; kb = kn*beta; A = -(kb kn^T) strictly-lower;
//   forward substitution in LDS -> T (T = A_final + I);
//   u = T @ (v*beta), w = T @ kb, attn = tril(qn kn^T), gbar = mean(gamma chunk).
//   All written to workspace (fp32, ~142.6 MB).
//
// Kernel B (scan; 16 bh x 16 dv-tiles = 256 blocks, 1 per CU):
//   per chunk: u_i = u_raw - w@S ; o = qn@S + attn@u_i ; S = gbar*S + kn^T@u_i.
//   S[256][16] fp32 lives in LDS; qn/kn re-derived from raw q,k per chunk.

namespace {

constexpr int  CS   = 32;
constexpr int  DK   = 256;
constexpr int  DV   = 256;
constexpr int  BH   = 16;
constexpr int  LSEQ = 4096;
constexpr int  NCH  = LSEQ / CS;        // 128 chunks per (b,h)
constexpr int  NCHUNKS = BH * NCH;      // 2048
constexpr int  LDP  = DK + 1;           // padded LDS row stride (257) - kills bank conflicts
constexpr int  DVT  = 16;               // dv-tile per scan block
constexpr int  SLD  = DVT + 1;          // padded S stride (17)

constexpr long WS_U   = 0;                                  // [NCHUNKS][CS][DV]
constexpr long WS_W   = (long)NCHUNKS * CS * DV;            // 16,777,216 floats
constexpr long WS_ATT = WS_W + (long)NCHUNKS * CS * DK;     // 33,554,432
constexpr long WS_GB  = WS_ATT + (long)NCHUNKS * CS * CS;   // 35,651,584
constexpr long WS_NEED_BYTES = (WS_GB + NCHUNKS) * 4;       // ~142.6 MB

constexpr long OUT_S  = (long)BH * LSEQ * DV;               // offset of final S in d_out

__global__ __launch_bounds__(256) void deltanet_chunk(
    const float* __restrict__ qg, const float* __restrict__ kg,
    const float* __restrict__ vg, const float* __restrict__ betag,
    const float* __restrict__ gammag, float* __restrict__ ws)
{
    __shared__ float kn[CS * LDP];   // normalized k chunk
    __shared__ float kb[CS * LDP];   // kn * beta
    __shared__ float vq[CS * LDP];   // v*beta, later reused for normalized q
    __shared__ float A[CS][CS];
    __shared__ float red[CS][8];
    __shared__ float rnorm[CS];
    __shared__ float betas[CS];
    __shared__ float incs[CS];

    float* u_out   = ws + WS_U;
    float* w_out   = ws + WS_W;
    float* att_out = ws + WS_ATT;
    float* gb_out  = ws + WS_GB;

    const int tid = threadIdx.x;
    const int chunk = blockIdx.x;                 // bh*128 + n (chunks tile L contiguously)
    const long gbase = (long)chunk * (CS * DK);

    // ---- stage k chunk + beta ----
    for (int it = 0; it < 8; ++it) {
        int f = tid + it * 256;                   // float4 index, 2048 total
        float4 x = reinterpret_cast<const float4*>(kg + gbase)[f];
        int r = f >> 6, c = (f & 63) << 2;
        float* p = kn + r * LDP + c;
        p[0] = x.x; p[1] = x.y; p[2] = x.z; p[3] = x.w;
    }
    if (tid < CS) betas[tid] = betag[chunk * CS + tid];
    __syncthreads();

    // ---- l2 norm of k rows; kb = kn*beta ----
    {
        int row = tid >> 3, sub = tid & 7;
        const float* rp = kn + row * LDP + sub * 32;
        float s = 0.f;
        #pragma unroll
        for (int i = 0; i < 32; ++i) s += rp[i] * rp[i];
        red[row][sub] = s;
    }
    __syncthreads();
    if (tid < CS) {
        float s = 0.f;
        #pragma unroll
        for (int i = 0; i < 8; ++i) s += red[tid][i];
        rnorm[tid] = rsqrtf(s + 1e-6f);
    }
    __syncthreads();
    for (int it = 0; it < 32; ++it) {
        int idx = tid + it * 256;
        int r = idx >> 8, c = idx & 255;
        float x = kn[r * LDP + c] * rnorm[r];
        kn[r * LDP + c] = x;
        kb[r * LDP + c] = x * betas[r];
    }
    __syncthreads();

    // ---- A = -(kb kn^T), strictly lower triangular ----
    for (int it = 0; it < 4; ++it) {
        int idx = tid + it * 256;
        int i = idx >> 5, j = idx & 31;
        float a = 0.f;
        if (i > j) {
            const float* pi = kb + i * LDP;
            const float* pj = kn + j * LDP;
            float s = 0.f;
            #pragma unroll 8
            for (int d = 0; d < DK; ++d) s += pi[d] * pj[d];
            a = -s;
        }
        A[i][j] = a;
    }
    __syncthreads();

    // ---- forward substitution: for i: A[i,:i] += A[i,:] @ A[:,:i] (pre-update row i) ----
    for (int i = 1; i < CS; ++i) {
        if (tid < i) {
            float s = 0.f;
            for (int j = tid + 1; j < i; ++j) s += A[i][j] * A[j][tid];
            incs[tid] = s;
        }
        __syncthreads();
        if (tid < i) A[i][tid] += incs[tid];
        __syncthreads();
    }

    // ---- stage v*beta ----
    for (int it = 0; it < 8; ++it) {
        int f = tid + it * 256;
        float4 x = reinterpret_cast<const float4*>(vg + gbase)[f];
        int r = f >> 6, c = (f & 63) << 2;
        float b = betas[r];
        float* p = vq + r * LDP + c;
        p[0] = x.x * b; p[1] = x.y * b; p[2] = x.z * b; p[3] = x.w * b;
    }
    __syncthreads();

    // ---- u = T@vb, w = T@kb  (one dk/dv column per thread) ----
    {
        const int d = tid;
        for (int i = 0; i < CS; ++i) {
            float su = vq[i * LDP + d];
            float sw = kb[i * LDP + d];
            for (int j = 0; j < i; ++j) {
                float a = A[i][j];
                su += a * vq[j * LDP + d];
                sw += a * kb[j * LDP + d];
            }
            u_out[gbase + i * DV + d] = su;
            w_out[gbase + i * DK + d] = sw;
        }
    }
    __syncthreads();

    // ---- stage q, normalize (reuse vq buffer) ----
    for (int it = 0; it < 8; ++it) {
        int f = tid + it * 256;
        float4 x = reinterpret_cast<const float4*>(qg + gbase)[f];
        int r = f >> 6, c = (f & 63) << 2;
        float* p = vq + r * LDP + c;
        p[0] = x.x; p[1] = x.y; p[2] = x.z; p[3] = x.w;
    }
    __syncthreads();
    {
        int row = tid >> 3, sub = tid & 7;
        const float* rp = vq + row * LDP + sub * 32;
        float s = 0.f;
        #pragma unroll
        for (int i = 0; i < 32; ++i) s += rp[i] * rp[i];
        red[row][sub] = s;
    }
    __syncthreads();
    if (tid < CS) {
        float s = 0.f;
        #pragma unroll
        for (int i = 0; i < 8; ++i) s += red[tid][i];
        rnorm[tid] = rsqrtf(s + 1e-6f);
    }
    __syncthreads();
    for (int it = 0; it < 32; ++it) {
        int idx = tid + it * 256;
        int r = idx >> 8, c = idx & 255;
        vq[r * LDP + c] *= rnorm[r];
    }
    __syncthreads();

    // ---- attn = tril(qn kn^T) incl diag ----
    for (int it = 0; it < 4; ++it) {
        int idx = tid + it * 256;
        int i = idx >> 5, j = idx & 31;
        float a = 0.f;
        if (i >= j) {
            const float* pi = vq + i * LDP;
            const float* pj = kn + j * LDP;
            float s = 0.f;
            #pragma unroll 8
            for (int d = 0; d < DK; ++d) s += pi[d] * pj[d];
            a = s;
        }
        att_out[(long)chunk * CS * CS + idx] = a;
    }

    // ---- gbar = mean(gamma chunk) ----
    if (tid == 0) {
        float s = 0.f;
        for (int i = 0; i < CS; ++i) s += gammag[chunk * CS + i];
        gb_out[chunk] = s * (1.f / CS);
    }
}

__global__ __launch_bounds__(256) void deltanet_scan(
    const float* __restrict__ qg, const float* __restrict__ kg,
    const float* __restrict__ ws, float* __restrict__ out)
{
    __shared__ float S[DK * SLD];     // 256x16 state tile (padded)
    __shared__ float qn[CS * LDP];
    __shared__ float kn[CS * LDP];
    __shared__ float wt[CS * LDP];
    __shared__ float att[CS][CS];
    __shared__ float ui[CS][DVT];
    __shared__ float redq[CS][8];
    __shared__ float redk[CS][8];
    __shared__ float rnq[CS], rnk[CS];

    const float* u_in   = ws + WS_U;
    const float* w_in   = ws + WS_W;
    const float* att_in = ws + WS_ATT;
    const float* gb_in  = ws + WS_GB;

    const int tid = threadIdx.x;
    const int bh = blockIdx.x >> 4;          // 16 dv tiles per bh
    const int vt = blockIdx.x & 15;
    const int v0 = vt * DVT;

    #pragma unroll
    for (int j = 0; j < DVT; ++j) S[tid * SLD + j] = 0.f;

    for (int n = 0; n < NCH; ++n) {
        const long ch = (long)bh * NCH + n;
        const long gbase = ch * (CS * DK);

        // ---- stage q,k,w chunks ----
        for (int it = 0; it < 8; ++it) {
            int f = tid + it * 256;
            int r = f >> 6, c = (f & 63) << 2;
            float4 xq = reinterpret_cast<const float4*>(qg  + gbase)[f];
            float4 xk = reinterpret_cast<const float4*>(kg  + gbase)[f];
            float4 xw = reinterpret_cast<const float4*>(w_in + gbase)[f];
            float* pq = qn + r * LDP + c; pq[0]=xq.x; pq[1]=xq.y; pq[2]=xq.z; pq[3]=xq.w;
            float* pk = kn + r * LDP + c; pk[0]=xk.x; pk[1]=xk.y; pk[2]=xk.z; pk[3]=xk.w;
            float* pw = wt + r * LDP + c; pw[0]=xw.x; pw[1]=xw.y; pw[2]=xw.z; pw[3]=xw.w;
        }
        // u slice + attn tile
        {
            int c = tid >> 4, j = tid & 15;
            ui[c][j]      = u_in[gbase + c * DV + v0 + j];
            ui[c + 16][j] = u_in[gbase + (c + 16) * DV + v0 + j];
        }
        for (int it = 0; it < 4; ++it) {
            int idx = tid + it * 256;
            att[idx >> 5][idx & 31] = att_in[ch * CS * CS + idx];
        }
        __syncthreads();

        // ---- normalize q,k rows ----
        {
            int row = tid >> 3, sub = tid & 7;
            const float* rq = qn + row * LDP + sub * 32;
            const float* rk = kn + row * LDP + sub * 32;
            float sq = 0.f, sk = 0.f;
            #pragma unroll
            for (int i = 0; i < 32; ++i) { sq += rq[i]*rq[i]; sk += rk[i]*rk[i]; }
            redq[row][sub] = sq; redk[row][sub] = sk;
        }
        __syncthreads();
        if (tid < CS) {
            float sq = 0.f, sk = 0.f;
            #pragma unroll
            for (int i = 0; i < 8; ++i) { sq += redq[tid][i]; sk += redk[tid][i]; }
            rnq[tid] = rsqrtf(sq + 1e-6f);
            rnk[tid] = rsqrtf(sk + 1e-6f);
        }
        __syncthreads();
        for (int it = 0; it < 32; ++it) {
            int idx = tid + it * 256;
            int r = idx >> 8, c = idx & 255;
            qn[r * LDP + c] *= rnq[r];
            kn[r * LDP + c] *= rnk[r];
        }
        __syncthreads();

        const float gb = gb_in[ch];

        // ---- u_i = u_raw - w @ S  (2 outputs per thread) ----
        {
            int j = tid & 15, c0 = tid >> 4;
            const float* wr0 = wt + c0 * LDP;
            const float* wr1 = wt + (c0 + 16) * LDP;
            float s0 = 0.f, s1 = 0.f;
            #pragma unroll 8
            for (int kk = 0; kk < DK; ++kk) {
                float sv = S[kk * SLD + j];
                s0 += wr0[kk] * sv;
                s1 += wr1[kk] * sv;
            }
            // in-place: only this thread touches ui[c0][j]/ui[c0+16][j] until the barrier
            ui[c0][j]      = ui[c0][j]      - s0;
            ui[c0 + 16][j] = ui[c0 + 16][j] - s1;
        }
        __syncthreads();

        // ---- o = qn @ S + attn @ u_i ----
        {
            int j = tid & 15, c0 = tid >> 4;
            const float* qr0 = qn + c0 * LDP;
            const float* qr1 = qn + (c0 + 16) * LDP;
            float s0 = 0.f, s1 = 0.f;
            #pragma unroll 8
            for (int kk = 0; kk < DK; ++kk) {
                float sv = S[kk * SLD + j];
                s0 += qr0[kk] * sv;
                s1 += qr1[kk] * sv;
            }
            #pragma unroll
            for (int d = 0; d < CS; ++d) {
                float uv = ui[d][j];
                s0 += att[c0][d] * uv;
                s1 += att[c0 + 16][d] * uv;
            }
            out[((long)bh * LSEQ + n * CS + c0) * DV + v0 + j]        = s0;
            out[((long)bh * LSEQ + n * CS + c0 + 16) * DV + v0 + j]   = s1;
        }
        __syncthreads();   // all reads of S done before update

        // ---- S = gb*S + kn^T @ u_i  (row k = tid) ----
        {
            float acc[DVT];
            #pragma unroll
            for (int j = 0; j < DVT; ++j) acc[j] = gb * S[tid * SLD + j];
            for (int c = 0; c < CS; ++c) {
                float kv = kn[c * LDP + tid];
                #pragma unroll
                for (int j = 0; j < DVT; ++j) acc[j] += kv * ui[c][j];
            }
            #pragma unroll
            for (int j = 0; j < DVT; ++j) S[tid * SLD + j] = acc[j];
        }
        __syncthreads();   // staging buffers reused next iteration
    }

    // ---- final state S -> d_out tail ----
    #pragma unroll
    for (int j = 0; j < DVT; ++j)
        out[OUT_S + ((long)bh * DK + tid) * DV + v0 + j] = S[tid * SLD + j];
}

} // namespace

extern "C" void kernel_launch(void* const* d_in, const int* in_sizes, int n_in,
                              void* d_out, int out_size, void* d_ws, size_t ws_size,
                              hipStream_t stream)
{
    (void)in_sizes; (void)n_in; (void)out_size;
    if (ws_size < (size_t)WS_NEED_BYTES) return;  // ws too small -> zeros (diagnostic absmax 1.99)

    const float* q     = (const float*)d_in[0];
    const float* k     = (const float*)d_in[1];
    const float* v     = (const float*)d_in[2];
    const float* beta  = (const float*)d_in[3];
    const float* gamma = (const float*)d_in[4];
    float* out = (float*)d_out;
    float* ws  = (float*)d_ws;

    hipLaunchKernelGGL(deltanet_chunk, dim3(NCHUNKS), dim3(256), 0, stream,
                       q, k, v, beta, gamma, ws);
    hipLaunchKernelGGL(deltanet_scan, dim3(BH * (DV / DVT)), dim3(256), 0, stream,
                       q, k, ws, out);
}

// Round 5
// 1045.739 us; speedup vs baseline: 3.8868x; 3.8868x over previous
//
#include <hip/hip_runtime.h>
#include <hip/hip_bf16.h>

// Round 5 resubmit (round 4 hit GPUAcquisitionTimeout; kernel never ran).
// MFMA scan. Kernel A normalizes q,k IN-PLACE (harness restores inputs
// before every launch) and emits u,w,att,gb (fp32 ws, unchanged layout).
// Kernel B holds S[256x16] in f32 MFMA accumulators (per-wave 32-row
// kk-slices), converts S to a bf16 operand slab once per chunk, and does
// all four products with mfma_f32_16x16x32_bf16. T14 prefetch: chunk n+1
// global loads issued at top of iter, written to LDS after last barrier.

namespace {

typedef __attribute__((ext_vector_type(8))) short bf16x8;   // 8 bf16 = 4 VGPR
typedef __attribute__((ext_vector_type(4))) short short4v;
typedef __attribute__((ext_vector_type(4))) float f32x4;

constexpr int  CS   = 32;
constexpr int  DK   = 256;
constexpr int  DV   = 256;
constexpr int  BH   = 16;
constexpr int  LSEQ = 4096;
constexpr int  NCH  = LSEQ / CS;        // 128
constexpr int  NCHUNKS = BH * NCH;      // 2048
constexpr int  LDP  = DK + 1;           // kernel A LDS pad
constexpr int  DVT  = 16;

// ws layout (unchanged from passing baseline)
constexpr long WS_U   = 0;
constexpr long WS_W   = (long)NCHUNKS * CS * DV;
constexpr long WS_ATT = WS_W + (long)NCHUNKS * CS * DK;
constexpr long WS_GB  = WS_ATT + (long)NCHUNKS * CS * CS;
constexpr long WS_NEED_BYTES = (WS_GB + NCHUNKS) * 4;

constexpr long OUT_S  = (long)BH * LSEQ * DV;

// scan LDS strides
constexpr int LW = 264;   // bf16 row stride for lw/lq/lSbT (16B-aligned rows, +8 pad)
constexpr int LT = 40;    // bf16 row stride for lkT/latt/luT
constexpr int LP = 17;    // f32 row stride for partials

__device__ inline short f2bs(float x) {
    __hip_bfloat16 h = __float2bfloat16(x);
    return __builtin_bit_cast(short, h);
}
__device__ inline f32x4 mfma16(bf16x8 a, bf16x8 b, f32x4 c) {
    return __builtin_amdgcn_mfma_f32_16x16x32_bf16(a, b, c, 0, 0, 0);
}

// ---------------- Kernel A (chunk-local precompute, fp32) ----------------
__global__ __launch_bounds__(256) void deltanet_chunk(
    float* __restrict__ qg, float* __restrict__ kg,
    const float* __restrict__ vg, const float* __restrict__ betag,
    const float* __restrict__ gammag, float* __restrict__ ws)
{
    __shared__ float kn[CS * LDP];
    __shared__ float kb[CS * LDP];
    __shared__ float vq[CS * LDP];
    __shared__ float A[CS][CS];
    __shared__ float red[CS][8];
    __shared__ float rnorm[CS];
    __shared__ float betas[CS];
    __shared__ float incs[CS];

    float* u_out   = ws + WS_U;
    float* w_out   = ws + WS_W;
    float* att_out = ws + WS_ATT;
    float* gb_out  = ws + WS_GB;

    const int tid = threadIdx.x;
    const int chunk = blockIdx.x;
    const long gbase = (long)chunk * (CS * DK);

    // stage k + beta
    for (int it = 0; it < 8; ++it) {
        int f = tid + it * 256;
        float4 x = reinterpret_cast<const float4*>(kg + gbase)[f];
        int r = f >> 6, c = (f & 63) << 2;
        float* p = kn + r * LDP + c;
        p[0] = x.x; p[1] = x.y; p[2] = x.z; p[3] = x.w;
    }
    if (tid < CS) betas[tid] = betag[chunk * CS + tid];
    __syncthreads();

    // l2norm k; kb = kn*beta
    {
        int row = tid >> 3, sub = tid & 7;
        const float* rp = kn + row * LDP + sub * 32;
        float s = 0.f;
        #pragma unroll
        for (int i = 0; i < 32; ++i) s += rp[i] * rp[i];
        red[row][sub] = s;
    }
    __syncthreads();
    if (tid < CS) {
        float s = 0.f;
        #pragma unroll
        for (int i = 0; i < 8; ++i) s += red[tid][i];
        rnorm[tid] = rsqrtf(s + 1e-6f);
    }
    __syncthreads();
    for (int it = 0; it < 32; ++it) {
        int idx = tid + it * 256;
        int r = idx >> 8, c = idx & 255;
        float x = kn[r * LDP + c] * rnorm[r];
        kn[r * LDP + c] = x;
        kb[r * LDP + c] = x * betas[r];
    }
    __syncthreads();

    // write back normalized k in place (scan reads kn directly)
    for (int it = 0; it < 8; ++it) {
        int f = tid + it * 256;
        int r = f >> 6, c = (f & 63) << 2;
        float4 x;
        x.x = kn[r*LDP+c]; x.y = kn[r*LDP+c+1]; x.z = kn[r*LDP+c+2]; x.w = kn[r*LDP+c+3];
        reinterpret_cast<float4*>(kg + gbase)[f] = x;
    }

    // A = -(kb kn^T) strictly lower
    for (int it = 0; it < 4; ++it) {
        int idx = tid + it * 256;
        int i = idx >> 5, j = idx & 31;
        float a = 0.f;
        if (i > j) {
            const float* pi = kb + i * LDP;
            const float* pj = kn + j * LDP;
            float s = 0.f;
            #pragma unroll 8
            for (int d = 0; d < DK; ++d) s += pi[d] * pj[d];
            a = -s;
        }
        A[i][j] = a;
    }
    __syncthreads();

    // forward substitution
    for (int i = 1; i < CS; ++i) {
        if (tid < i) {
            float s = 0.f;
            for (int j = tid + 1; j < i; ++j) s += A[i][j] * A[j][tid];
            incs[tid] = s;
        }
        __syncthreads();
        if (tid < i) A[i][tid] += incs[tid];
        __syncthreads();
    }

    // stage v*beta
    for (int it = 0; it < 8; ++it) {
        int f = tid + it * 256;
        float4 x = reinterpret_cast<const float4*>(vg + gbase)[f];
        int r = f >> 6, c = (f & 63) << 2;
        float b = betas[r];
        float* p = vq + r * LDP + c;
        p[0] = x.x * b; p[1] = x.y * b; p[2] = x.z * b; p[3] = x.w * b;
    }
    __syncthreads();

    // u = T@vb, w = T@kb
    {
        const int d = tid;
        for (int i = 0; i < CS; ++i) {
            float su = vq[i * LDP + d];
            float sw = kb[i * LDP + d];
            for (int j = 0; j < i; ++j) {
                float a = A[i][j];
                su += a * vq[j * LDP + d];
                sw += a * kb[j * LDP + d];
            }
            u_out[gbase + i * DV + d] = su;
            w_out[gbase + i * DK + d] = sw;
        }
    }
    __syncthreads();

    // stage q, normalize (reuse vq)
    for (int it = 0; it < 8; ++it) {
        int f = tid + it * 256;
        float4 x = reinterpret_cast<const float4*>(qg + gbase)[f];
        int r = f >> 6, c = (f & 63) << 2;
        float* p = vq + r * LDP + c;
        p[0] = x.x; p[1] = x.y; p[2] = x.z; p[3] = x.w;
    }
    __syncthreads();
    {
        int row = tid >> 3, sub = tid & 7;
        const float* rp = vq + row * LDP + sub * 32;
        float s = 0.f;
        #pragma unroll
        for (int i = 0; i < 32; ++i) s += rp[i] * rp[i];
        red[row][sub] = s;
    }
    __syncthreads();
    if (tid < CS) {
        float s = 0.f;
        #pragma unroll
        for (int i = 0; i < 8; ++i) s += red[tid][i];
        rnorm[tid] = rsqrtf(s + 1e-6f);
    }
    __syncthreads();
    for (int it = 0; it < 32; ++it) {
        int idx = tid + it * 256;
        int r = idx >> 8, c = idx & 255;
        vq[r * LDP + c] *= rnorm[r];
    }
    __syncthreads();

    // write back normalized q in place
    for (int it = 0; it < 8; ++it) {
        int f = tid + it * 256;
        int r = f >> 6, c = (f & 63) << 2;
        float4 x;
        x.x = vq[r*LDP+c]; x.y = vq[r*LDP+c+1]; x.z = vq[r*LDP+c+2]; x.w = vq[r*LDP+c+3];
        reinterpret_cast<float4*>(qg + gbase)[f] = x;
    }

    // attn = tril(qn kn^T)
    for (int it = 0; it < 4; ++it) {
        int idx = tid + it * 256;
        int i = idx >> 5, j = idx & 31;
        float a = 0.f;
        if (i >= j) {
            const float* pi = vq + i * LDP;
            const float* pj = kn + j * LDP;
            float s = 0.f;
            #pragma unroll 8
            for (int d = 0; d < DK; ++d) s += pi[d] * pj[d];
            a = s;
        }
        att_out[(long)chunk * CS * CS + idx] = a;
    }

    if (tid == 0) {
        float s = 0.f;
        for (int i = 0; i < CS; ++i) s += gammag[chunk * CS + i];
        gb_out[chunk] = s * (1.f / CS);
    }
}

// ---------------- Kernel B (MFMA scan) ----------------
// 256 blocks = 16 bh x 16 j-tiles; 512 threads = 8 waves; wave wv owns
// S rows [32*wv, 32*wv+32) as two f32x4 accumulator tiles.
__global__ __launch_bounds__(512) void deltanet_scan_mfma(
    const float* __restrict__ qg, const float* __restrict__ kg,
    const float* __restrict__ ws, float* __restrict__ out)
{
    __shared__ short lw  [32 * LW];    // w rows, bf16
    __shared__ short lq  [32 * LW];    // qn rows, bf16
    __shared__ short lkT [256 * LT];   // kn^T (kk-major), bf16
    __shared__ short latt[32 * LT];    // att rows, bf16
    __shared__ short lSbT[16 * LW];    // S^T operand: [j][kk], bf16
    __shared__ short luT [16 * LT];    // u_i^T: [j][c], bf16
    __shared__ float lpart[8 * 32 * LP]; // per-wave partials (u then o)

    const float* u_in   = ws + WS_U;
    const float* w_in   = ws + WS_W;
    const float* att_in = ws + WS_ATT;
    const float* gb_in  = ws + WS_GB;

    const int tid = threadIdx.x;
    const int wv  = tid >> 6;
    const int ln  = tid & 63;
    const int l16 = ln & 15;          // frag row/col index
    const int lh  = ln >> 4;          // frag k-group
    const int bh  = blockIdx.x >> 4;
    const int v0  = (blockIdx.x & 15) * DVT;
    const int K0  = wv * 32;          // this wave's kk-slice

    const int rc = tid >> 4;          // reduce mapping: c
    const int rj = tid & 15;          //                 j

    f32x4 St0{}, St1{};               // S rows K0..K0+16, K0+16..K0+32 (col v0+l16)

    float4 pw[4], pq[4];
    float  pk[16];
    float  pa[2];
    float  pu, pgb;

    auto issue_prefetch = [&](int n1) {
        const long ch  = (long)bh * NCH + n1;
        const long gb8 = ch * (CS * DK);
        #pragma unroll
        for (int it = 0; it < 4; ++it) {
            int f = tid + it * 512;
            pw[it] = reinterpret_cast<const float4*>(w_in + gb8)[f];
            pq[it] = reinterpret_cast<const float4*>(qg  + gb8)[f];
        }
        #pragma unroll
        for (int it = 0; it < 4; ++it) {
            int idx = tid + it * 512;
            int kk = idx & 255, cg = (idx >> 8) * 4;
            #pragma unroll
            for (int i = 0; i < 4; ++i)
                pk[it * 4 + i] = kg[gb8 + (long)(cg + i) * DK + kk];
        }
        #pragma unroll
        for (int it = 0; it < 2; ++it)
            pa[it] = att_in[ch * CS * CS + tid + it * 512];
        pu  = u_in[gb8 + (long)rc * DV + v0 + rj];
        pgb = gb_in[ch];
    };

    auto stage_write = [&]() {
        #pragma unroll
        for (int it = 0; it < 4; ++it) {
            int f = tid + it * 512;
            int r = f >> 6, c4 = (f & 63) << 2;
            short4v sw, sq;
            const float* xw = reinterpret_cast<const float*>(&pw[it]);
            const float* xq = reinterpret_cast<const float*>(&pq[it]);
            #pragma unroll
            for (int i = 0; i < 4; ++i) { sw[i] = f2bs(xw[i]); sq[i] = f2bs(xq[i]); }
            *reinterpret_cast<short4v*>(&lw[r * LW + c4]) = sw;
            *reinterpret_cast<short4v*>(&lq[r * LW + c4]) = sq;
        }
        #pragma unroll
        for (int it = 0; it < 4; ++it) {
            int idx = tid + it * 512;
            int kk = idx & 255, cg = (idx >> 8) * 4;
            short4v sk;
            #pragma unroll
            for (int i = 0; i < 4; ++i) sk[i] = f2bs(pk[it * 4 + i]);
            *reinterpret_cast<short4v*>(&lkT[kk * LT + cg]) = sk;
        }
        #pragma unroll
        for (int it = 0; it < 2; ++it) {
            int idx = tid + it * 512;
            latt[(idx >> 5) * LT + (idx & 31)] = f2bs(pa[it]);
        }
    };

    // A/B fragment load: element [row0+l16][col0 + lh*8 + e], rows stride ld
    auto frag = [&](const short* base, int row0, int col0, int ld) -> bf16x8 {
        return *reinterpret_cast<const bf16x8*>(base + (row0 + l16) * ld + col0 + lh * 8);
    };

    auto writePart = [&](const f32x4& d, int ct) {
        #pragma unroll
        for (int i = 0; i < 4; ++i)
            lpart[(wv * 32 + ct * 16 + lh * 4 + i) * LP + l16] = d[i];
    };

    auto write_SbT = [&]() {
        #pragma unroll
        for (int t = 0; t < 2; ++t) {
            f32x4 s = t ? St1 : St0;
            short4v sv;
            #pragma unroll
            for (int i = 0; i < 4; ++i) sv[i] = f2bs(s[i]);
            *reinterpret_cast<short4v*>(&lSbT[l16 * LW + K0 + t * 16 + lh * 4]) = sv;
        }
    };

    // prologue: S = 0, stage chunk 0
    for (int i = tid; i < 16 * LW; i += 512) lSbT[i] = 0;
    issue_prefetch(0);
    stage_write();
    float ureg = pu, gbr = pgb;
    __syncthreads();

    for (int n = 0; n < NCH; ++n) {
        issue_prefetch(n + 1 < NCH ? n + 1 : NCH - 1);

        // P1: partial w@S for this wave's kk-slice
        {
            bf16x8 bS = frag(lSbT, 0, K0, LW);
            f32x4 d0{}, d1{};
            d0 = mfma16(frag(lw, 0,  K0, LW), bS, d0);
            d1 = mfma16(frag(lw, 16, K0, LW), bS, d1);
            writePart(d0, 0); writePart(d1, 1);
        }
        __syncthreads();

        // P1-reduce: u_i = u_raw - sum(partials); publish bf16 u_i^T
        {
            float s = 0.f;
            #pragma unroll
            for (int p = 0; p < 8; ++p) s += lpart[(p * 32 + rc) * LP + rj];
            luT[rj * LT + rc] = f2bs(ureg - s);
        }
        __syncthreads();

        // P2: partial qn@S (+ att@u_i on waves 0,1)
        {
            bf16x8 bS = frag(lSbT, 0, K0, LW);
            f32x4 e0{}, e1{};
            e0 = mfma16(frag(lq, 0,  K0, LW), bS, e0);
            e1 = mfma16(frag(lq, 16, K0, LW), bS, e1);
            if (wv < 2) {
                bf16x8 bU = frag(luT, 0, 0, LT);
                if (wv == 0) e0 = mfma16(frag(latt, 0,  0, LT), bU, e0);
                else         e1 = mfma16(frag(latt, 16, 0, LT), bU, e1);
            }
            writePart(e0, 0); writePart(e1, 1);
        }
        __syncthreads();

        // P2-reduce: o -> global
        {
            float s = 0.f;
            #pragma unroll
            for (int p = 0; p < 8; ++p) s += lpart[(p * 32 + rc) * LP + rj];
            out[((long)bh * LSEQ + n * CS + rc) * DV + v0 + rj] = s;
        }

        // P3: S = gb*S + kn^T @ u_i (this wave's rows)
        {
            bf16x8 bU = frag(luT, 0, 0, LT);
            #pragma unroll
            for (int i = 0; i < 4; ++i) { St0[i] *= gbr; St1[i] *= gbr; }
            St0 = mfma16(frag(lkT, K0,      0, LT), bU, St0);
            St1 = mfma16(frag(lkT, K0 + 16, 0, LT), bU, St1);
        }
        __syncthreads();

        // stage chunk n+1 + refresh S operand slab
        stage_write();
        write_SbT();
        ureg = pu; gbr = pgb;
        __syncthreads();
    }

    // final S -> out tail
    #pragma unroll
    for (int t = 0; t < 2; ++t) {
        f32x4 s = t ? St1 : St0;
        #pragma unroll
        for (int i = 0; i < 4; ++i) {
            int kk = K0 + t * 16 + lh * 4 + i;
            out[OUT_S + ((long)bh * DK + kk) * DV + v0 + l16] = s[i];
        }
    }
}

} // namespace

extern "C" void kernel_launch(void* const* d_in, const int* in_sizes, int n_in,
                              void* d_out, int out_size, void* d_ws, size_t ws_size,
                              hipStream_t stream)
{
    (void)in_sizes; (void)n_in; (void)out_size;
    if (ws_size < (size_t)WS_NEED_BYTES) return;

    float* q     = (float*)d_in[0];
    float* k     = (float*)d_in[1];
    const float* v     = (const float*)d_in[2];
    const float* beta  = (const float*)d_in[3];
    const float* gamma = (const float*)d_in[4];
    float* out = (float*)d_out;
    float* ws  = (float*)d_ws;

    hipLaunchKernelGGL(deltanet_chunk, dim3(NCHUNKS), dim3(256), 0, stream,
                       q, k, v, beta, gamma, ws);
    hipLaunchKernelGGL(deltanet_scan_mfma, dim3(BH * (DV / DVT)), dim3(512), 0, stream,
                       q, k, ws, out);
}

// Round 6
// 584.111 us; speedup vs baseline: 6.9585x; 1.7903x over previous
//
#include <hip/hip_runtime.h>
#include <hip/hip_bf16.h>

// Round 6: MFMA-ize kernel A (was 552us, LDS-pipe/latency bound at 1 blk/CU).
// - register normalize (shfl) -> bf16 LDS slabs, no fp32 LDS staging
// - A, att via wave-quadrant MFMA K=256; u,w via T@X MFMA K=32
// - fwd-substitution kept verbatim (proven correct)
// - ws now scan-ready: u fp32, w/kT/att bf16 (132 MB < proven 142.6 MB grant)
// - scan staging becomes plain bf16x8 copies (k-transpose gather deleted)

namespace {

typedef __attribute__((ext_vector_type(8))) short bf16x8;
typedef __attribute__((ext_vector_type(4))) short short4v;
typedef __attribute__((ext_vector_type(4))) float f32x4;

constexpr int  CS   = 32;
constexpr int  DK   = 256;
constexpr int  DV   = 256;
constexpr int  BH   = 16;
constexpr int  LSEQ = 4096;
constexpr int  NCH  = LSEQ / CS;        // 128
constexpr int  NCHUNKS = BH * NCH;      // 2048
constexpr int  DVT  = 16;

// ws layout: u f32 [2048][32][256] | w bf16 | kT bf16 [256][32] | att bf16 | gb f32
constexpr long WSU_F   = 0;             // float index
constexpr long WSW_S   = 33554432L;     // short index (byte 67,108,864)
constexpr long WSKT_S  = 50331648L;     // short index
constexpr long WSATT_S = 67108864L;     // short index
constexpr long WSGB_F  = 34603008L;     // float index (byte 138,412,032)
constexpr long WS_NEED_BYTES = 138420224L;

constexpr long OUT_S  = (long)BH * LSEQ * DV;

// kernel A LDS strides (shorts)
constexpr int LWA = 264;   // 32-row bf16 slabs; 528B row stride, 16B-aligned frags
constexpr int LTT = 40;    // T rows
// scan LDS strides
constexpr int LW = 264;
constexpr int LT = 40;
constexpr int LP = 17;

__device__ inline short f2bs(float x) {
    __hip_bfloat16 h = __float2bfloat16(x);
    return __builtin_bit_cast(short, h);
}
__device__ inline f32x4 mfma16(bf16x8 a, bf16x8 b, f32x4 c) {
    return __builtin_amdgcn_mfma_f32_16x16x32_bf16(a, b, c, 0, 0, 0);
}

// ---------------- Kernel A (MFMA chunk precompute) ----------------
// 256 threads = 4 waves. Wave wv -> 16x16 quadrant (wv>>1, wv&1) for the
// 32x32 products; 8 of 32 output tiles for the T@X products.
__global__ __launch_bounds__(256) void deltanet_chunk_mfma(
    float* __restrict__ qg, const float* __restrict__ kg,
    const float* __restrict__ vg, const float* __restrict__ betag,
    const float* __restrict__ gammag, float* __restrict__ ws)
{
    __shared__ short knb[32 * LWA];   // normalized k, bf16
    __shared__ short kbb[32 * LWA];   // kn*beta, bf16
    __shared__ short vqb[32 * LWA];   // v*beta, later qn, bf16
    __shared__ float Afp[32][33];
    __shared__ short Tb[32 * LTT];
    __shared__ float incs[CS];

    float* u_out   = ws + WSU_F;
    short* wsS     = (short*)ws;
    short* w_out   = wsS + WSW_S;
    short* kt_out  = wsS + WSKT_S;
    short* att_out = wsS + WSATT_S;
    float* gb_out  = ws + WSGB_F;

    const int tid = threadIdx.x;
    const int wv  = tid >> 6, ln = tid & 63, l16 = ln & 15, lh = ln >> 4;
    const int chunk = blockIdx.x;
    const long gbase = (long)chunk * (CS * DK);
    const int r = tid >> 3, sub = tid & 7;          // staging: row r, seg sub

    const float beta_r = betag[chunk * CS + r];

    // gb = mean(gamma) via lanes 0..31 of wave 0
    if (tid < 32) {
        float g = gammag[chunk * CS + tid];
        g += __shfl_xor(g, 1);  g += __shfl_xor(g, 2);  g += __shfl_xor(g, 4);
        g += __shfl_xor(g, 8);  g += __shfl_xor(g, 16);
        if (tid == 0) gb_out[chunk] = g * (1.f / CS);
    }

    // ---- phase 1: k -> knb (l2norm), kbb (*beta) ----
    {
        float4 kx[8];
        const float4* src = reinterpret_cast<const float4*>(kg + gbase + (long)r * DK + sub * 32);
        #pragma unroll
        for (int i = 0; i < 8; ++i) kx[i] = src[i];
        float ss = 0.f;
        #pragma unroll
        for (int i = 0; i < 8; ++i)
            ss += kx[i].x*kx[i].x + kx[i].y*kx[i].y + kx[i].z*kx[i].z + kx[i].w*kx[i].w;
        ss += __shfl_xor(ss, 1); ss += __shfl_xor(ss, 2); ss += __shfl_xor(ss, 4);
        const float rn = rsqrtf(ss + 1e-6f);
        #pragma unroll
        for (int i = 0; i < 8; ++i) {
            float n0 = kx[i].x*rn, n1 = kx[i].y*rn, n2 = kx[i].z*rn, n3 = kx[i].w*rn;
            short4v sn, sb;
            sn[0]=f2bs(n0); sn[1]=f2bs(n1); sn[2]=f2bs(n2); sn[3]=f2bs(n3);
            sb[0]=f2bs(n0*beta_r); sb[1]=f2bs(n1*beta_r); sb[2]=f2bs(n2*beta_r); sb[3]=f2bs(n3*beta_r);
            *reinterpret_cast<short4v*>(&knb[r*LWA + sub*32 + i*4]) = sn;
            *reinterpret_cast<short4v*>(&kbb[r*LWA + sub*32 + i*4]) = sb;
        }
    }
    __syncthreads();

    // ---- phase 2: A = -(kbb . knb^T), strictly lower, fp32 in LDS ----
    {
        const int qi = wv >> 1, qj = wv & 1;
        f32x4 d{};
        #pragma unroll
        for (int k0 = 0; k0 < 256; k0 += 32) {
            bf16x8 a = *reinterpret_cast<const bf16x8*>(&kbb[(qi*16 + l16)*LWA + k0 + lh*8]);
            bf16x8 b = *reinterpret_cast<const bf16x8*>(&knb[(qj*16 + l16)*LWA + k0 + lh*8]);
            d = mfma16(a, b, d);
        }
        #pragma unroll
        for (int i = 0; i < 4; ++i) {
            int ig = qi*16 + lh*4 + i, jg = qj*16 + l16;
            Afp[ig][jg] = (ig > jg) ? -d[i] : 0.f;
        }
    }
    __syncthreads();

    // ---- phase 3: forward substitution (proven barriered version) ----
    for (int i = 1; i < CS; ++i) {
        if (tid < i) {
            float s = 0.f;
            for (int j = tid + 1; j < i; ++j) s += Afp[i][j] * Afp[j][tid];
            incs[tid] = s;
        }
        __syncthreads();
        if (tid < i) Afp[i][tid] += incs[tid];
        __syncthreads();
    }

    // ---- phase 4: Tb (bf16 T = A + I), v -> vqb (*beta) ----
    {
        float4 vx[8];
        const float4* src = reinterpret_cast<const float4*>(vg + gbase + (long)r * DK + sub * 32);
        #pragma unroll
        for (int i = 0; i < 8; ++i) vx[i] = src[i];

        const int idx4 = tid * 4;
        const int ti = idx4 >> 5, tj0 = idx4 & 31;
        short4v tv;
        #pragma unroll
        for (int j = 0; j < 4; ++j) {
            int tj = tj0 + j;
            float val = (ti == tj) ? 1.f : ((ti > tj) ? Afp[ti][tj] : 0.f);
            tv[j] = f2bs(val);
        }
        *reinterpret_cast<short4v*>(&Tb[ti*LTT + tj0]) = tv;

        #pragma unroll
        for (int i = 0; i < 8; ++i) {
            short4v sv;
            sv[0]=f2bs(vx[i].x*beta_r); sv[1]=f2bs(vx[i].y*beta_r);
            sv[2]=f2bs(vx[i].z*beta_r); sv[3]=f2bs(vx[i].w*beta_r);
            *reinterpret_cast<short4v*>(&vqb[r*LWA + sub*32 + i*4]) = sv;
        }
    }
    __syncthreads();

    // ---- phase 5: u = T@vb (fp32 out), w = T@kb (bf16 out); kT export ----
    {
        #pragma unroll
        for (int t8 = 0; t8 < 8; ++t8) {
            const int tile = wv*8 + t8, m = tile >> 4, c = tile & 15;
            bf16x8 a = *reinterpret_cast<const bf16x8*>(&Tb[(m*16 + l16)*LTT + lh*8]);
            bf16x8 bu, bw;
            #pragma unroll
            for (int e = 0; e < 8; ++e) {
                bu[e] = vqb[(lh*8 + e)*LWA + c*16 + l16];
                bw[e] = kbb[(lh*8 + e)*LWA + c*16 + l16];
            }
            f32x4 du = mfma16(a, bu, f32x4{});
            f32x4 dw = mfma16(a, bw, f32x4{});
            #pragma unroll
            for (int i = 0; i < 4; ++i) {
                const int row = m*16 + lh*4 + i, col = c*16 + l16;
                u_out[gbase + (long)row * DV + col] = du[i];
                w_out[(long)chunk * 8192 + row * 256 + col] = f2bs(dw[i]);
            }
        }
        // kT[kk=tid][c] = kn[c][kk]  (column reads are 2-way/free; 64B/lane stores)
        #pragma unroll
        for (int i = 0; i < 4; ++i) {
            bf16x8 t;
            #pragma unroll
            for (int e = 0; e < 8; ++e) t[e] = knb[(i*8 + e)*LWA + tid];
            *reinterpret_cast<bf16x8*>(&kt_out[(long)chunk * 8192 + tid * 32 + i*8]) = t;
        }
    }
    __syncthreads();   // vqb reads done

    // ---- phase 6: q -> normalize -> writeback fp32 in-place + vqb bf16 ----
    {
        float4 qx[8];
        const float4* src = reinterpret_cast<const float4*>(qg + gbase + (long)r * DK + sub * 32);
        #pragma unroll
        for (int i = 0; i < 8; ++i) qx[i] = src[i];
        float ss = 0.f;
        #pragma unroll
        for (int i = 0; i < 8; ++i)
            ss += qx[i].x*qx[i].x + qx[i].y*qx[i].y + qx[i].z*qx[i].z + qx[i].w*qx[i].w;
        ss += __shfl_xor(ss, 1); ss += __shfl_xor(ss, 2); ss += __shfl_xor(ss, 4);
        const float rn = rsqrtf(ss + 1e-6f);
        float4* dst = reinterpret_cast<float4*>(qg + gbase + (long)r * DK + sub * 32);
        #pragma unroll
        for (int i = 0; i < 8; ++i) {
            float4 n4; n4.x=qx[i].x*rn; n4.y=qx[i].y*rn; n4.z=qx[i].z*rn; n4.w=qx[i].w*rn;
            dst[i] = n4;
            short4v sq; sq[0]=f2bs(n4.x); sq[1]=f2bs(n4.y); sq[2]=f2bs(n4.z); sq[3]=f2bs(n4.w);
            *reinterpret_cast<short4v*>(&vqb[r*LWA + sub*32 + i*4]) = sq;
        }
    }
    __syncthreads();

    // ---- phase 7: att = tril(qn . kn^T) -> bf16 ws ----
    {
        const int qi = wv >> 1, qj = wv & 1;
        f32x4 d{};
        #pragma unroll
        for (int k0 = 0; k0 < 256; k0 += 32) {
            bf16x8 a = *reinterpret_cast<const bf16x8*>(&vqb[(qi*16 + l16)*LWA + k0 + lh*8]);
            bf16x8 b = *reinterpret_cast<const bf16x8*>(&knb[(qj*16 + l16)*LWA + k0 + lh*8]);
            d = mfma16(a, b, d);
        }
        #pragma unroll
        for (int i = 0; i < 4; ++i) {
            int ig = qi*16 + lh*4 + i, jg = qj*16 + l16;
            att_out[(long)chunk * 1024 + ig*32 + jg] = f2bs((ig >= jg) ? d[i] : 0.f);
        }
    }
}

// ---------------- Kernel B (MFMA scan) ----------------
// 256 blocks = 16 bh x 16 j-tiles; 512 threads = 8 waves; wave wv owns
// S rows [32*wv, 32*wv+32) as two f32x4 accumulator tiles.
__global__ __launch_bounds__(512) void deltanet_scan_mfma(
    const float* __restrict__ qg, const float* __restrict__ ws,
    float* __restrict__ out)
{
    __shared__ short lw  [32 * LW];
    __shared__ short lq  [32 * LW];
    __shared__ short lkT [256 * LT];
    __shared__ short latt[32 * LT];
    __shared__ short lSbT[16 * LW];
    __shared__ short luT [16 * LT];
    __shared__ float lpart[8 * 32 * LP];

    const float* u_in   = ws + WSU_F;
    const short* wsS    = (const short*)ws;
    const short* w_in   = wsS + WSW_S;
    const short* kt_in  = wsS + WSKT_S;
    const short* att_in = wsS + WSATT_S;
    const float* gb_in  = ws + WSGB_F;

    const int tid = threadIdx.x;
    const int wv  = tid >> 6;
    const int ln  = tid & 63;
    const int l16 = ln & 15;
    const int lh  = ln >> 4;
    const int bh  = blockIdx.x >> 4;
    const int v0  = (blockIdx.x & 15) * DVT;
    const int K0  = wv * 32;

    const int rc = tid >> 4;
    const int rj = tid & 15;

    f32x4 St0{}, St1{};

    bf16x8 pw8[2], pk8[2];
    float4 pq[4];
    unsigned int pa;
    float  pu, pgb;

    auto issue_prefetch = [&](int n1) {
        const long ch  = (long)bh * NCH + n1;
        const long off = ch * 8192L;
        #pragma unroll
        for (int it = 0; it < 2; ++it) {
            int idx = tid + it * 512;
            pw8[it] = *reinterpret_cast<const bf16x8*>(w_in  + off + (long)idx * 8);
            pk8[it] = *reinterpret_cast<const bf16x8*>(kt_in + off + (long)idx * 8);
        }
        #pragma unroll
        for (int it = 0; it < 4; ++it) {
            int f = tid + it * 512;
            pq[it] = reinterpret_cast<const float4*>(qg + off)[f];
        }
        pa  = *reinterpret_cast<const unsigned int*>(att_in + ch * 1024 + tid * 2);
        pu  = u_in[off + (long)rc * DV + v0 + rj];
        pgb = gb_in[ch];
    };

    auto stage_write = [&]() {
        #pragma unroll
        for (int it = 0; it < 2; ++it) {
            int idx = tid + it * 512;
            *reinterpret_cast<bf16x8*>(&lw[(idx >> 5) * LW + (idx & 31) * 8]) = pw8[it];
            *reinterpret_cast<bf16x8*>(&lkT[(idx >> 2) * LT + (idx & 3) * 8]) = pk8[it];
        }
        #pragma unroll
        for (int it = 0; it < 4; ++it) {
            int f = tid + it * 512;
            int r = f >> 6, c4 = (f & 63) << 2;
            short4v sq;
            const float* xq = reinterpret_cast<const float*>(&pq[it]);
            #pragma unroll
            for (int i = 0; i < 4; ++i) sq[i] = f2bs(xq[i]);
            *reinterpret_cast<short4v*>(&lq[r * LW + c4]) = sq;
        }
        *reinterpret_cast<unsigned int*>(&latt[(tid >> 4) * LT + (tid & 15) * 2]) = pa;
    };

    auto frag = [&](const short* base, int row0, int col0, int ld) -> bf16x8 {
        return *reinterpret_cast<const bf16x8*>(base + (row0 + l16) * ld + col0 + lh * 8);
    };

    auto writePart = [&](const f32x4& d, int ct) {
        #pragma unroll
        for (int i = 0; i < 4; ++i)
            lpart[(wv * 32 + ct * 16 + lh * 4 + i) * LP + l16] = d[i];
    };

    auto write_SbT = [&]() {
        #pragma unroll
        for (int t = 0; t < 2; ++t) {
            f32x4 s = t ? St1 : St0;
            short4v sv;
            #pragma unroll
            for (int i = 0; i < 4; ++i) sv[i] = f2bs(s[i]);
            *reinterpret_cast<short4v*>(&lSbT[l16 * LW + K0 + t * 16 + lh * 4]) = sv;
        }
    };

    for (int i = tid; i < 16 * LW; i += 512) lSbT[i] = 0;
    issue_prefetch(0);
    stage_write();
    float ureg = pu, gbr = pgb;
    __syncthreads();

    for (int n = 0; n < NCH; ++n) {
        issue_prefetch(n + 1 < NCH ? n + 1 : NCH - 1);

        // P1: partial w@S for this wave's kk-slice
        {
            bf16x8 bS = frag(lSbT, 0, K0, LW);
            f32x4 d0{}, d1{};
            d0 = mfma16(frag(lw, 0,  K0, LW), bS, d0);
            d1 = mfma16(frag(lw, 16, K0, LW), bS, d1);
            writePart(d0, 0); writePart(d1, 1);
        }
        __syncthreads();

        // P1-reduce: u_i = u_raw - sum(partials); publish bf16 u_i^T
        {
            float s = 0.f;
            #pragma unroll
            for (int p = 0; p < 8; ++p) s += lpart[(p * 32 + rc) * LP + rj];
            luT[rj * LT + rc] = f2bs(ureg - s);
        }
        __syncthreads();

        // P2: partial qn@S (+ att@u_i on waves 0,1)
        {
            bf16x8 bS = frag(lSbT, 0, K0, LW);
            f32x4 e0{}, e1{};
            e0 = mfma16(frag(lq, 0,  K0, LW), bS, e0);
            e1 = mfma16(frag(lq, 16, K0, LW), bS, e1);
            if (wv < 2) {
                bf16x8 bU = frag(luT, 0, 0, LT);
                if (wv == 0) e0 = mfma16(frag(latt, 0,  0, LT), bU, e0);
                else         e1 = mfma16(frag(latt, 16, 0, LT), bU, e1);
            }
            writePart(e0, 0); writePart(e1, 1);
        }
        __syncthreads();

        // P2-reduce: o -> global
        {
            float s = 0.f;
            #pragma unroll
            for (int p = 0; p < 8; ++p) s += lpart[(p * 32 + rc) * LP + rj];
            out[((long)bh * LSEQ + n * CS + rc) * DV + v0 + rj] = s;
        }

        // P3: S = gb*S + kn^T @ u_i (this wave's rows)
        {
            bf16x8 bU = frag(luT, 0, 0, LT);
            #pragma unroll
            for (int i = 0; i < 4; ++i) { St0[i] *= gbr; St1[i] *= gbr; }
            St0 = mfma16(frag(lkT, K0,      0, LT), bU, St0);
            St1 = mfma16(frag(lkT, K0 + 16, 0, LT), bU, St1);
        }
        __syncthreads();

        stage_write();
        write_SbT();
        ureg = pu; gbr = pgb;
        __syncthreads();
    }

    #pragma unroll
    for (int t = 0; t < 2; ++t) {
        f32x4 s = t ? St1 : St0;
        #pragma unroll
        for (int i = 0; i < 4; ++i) {
            int kk = K0 + t * 16 + lh * 4 + i;
            out[OUT_S + ((long)bh * DK + kk) * DV + v0 + l16] = s[i];
        }
    }
}

} // namespace

extern "C" void kernel_launch(void* const* d_in, const int* in_sizes, int n_in,
                              void* d_out, int out_size, void* d_ws, size_t ws_size,
                              hipStream_t stream)
{
    (void)in_sizes; (void)n_in; (void)out_size;
    if (ws_size < (size_t)WS_NEED_BYTES) return;

    float* q     = (float*)d_in[0];
    const float* k     = (const float*)d_in[1];
    const float* v     = (const float*)d_in[2];
    const float* beta  = (const float*)d_in[3];
    const float* gamma = (const float*)d_in[4];
    float* out = (float*)d_out;
    float* ws  = (float*)d_ws;

    hipLaunchKernelGGL(deltanet_chunk_mfma, dim3(NCHUNKS), dim3(256), 0, stream,
                       q, k, v, beta, gamma, ws);
    hipLaunchKernelGGL(deltanet_scan_mfma, dim3(BH * (DV / DVT)), dim3(512), 0, stream,
                       q, ws, out);
}